// Round 1
// baseline (1823.355 us; speedup 1.0000x reference)
//
#include <hip/hip_runtime.h>

#define NPTS 400000
#define MVOX 300000
#define KK 27
#define KD 8
#define CIN 4
#define C0 32
#define NCLS 19
#define EPS 1e-5f

// ---------------- voxelization ----------------
__global__ void vox_accum(const float* __restrict__ pf, const int* __restrict__ iq,
                          float* __restrict__ counts, float* __restrict__ vox) {
    int i = blockIdx.x * blockDim.x + threadIdx.x;
    if (i >= NPTS) return;
    int q = iq[i];
    float4 f = *reinterpret_cast<const float4*>(pf + (size_t)i * CIN);
    atomicAdd(&counts[q], 1.0f);
    atomicAdd(&vox[q * CIN + 0], f.x);
    atomicAdd(&vox[q * CIN + 1], f.y);
    atomicAdd(&vox[q * CIN + 2], f.z);
    atomicAdd(&vox[q * CIN + 3], f.w);
}

__global__ void vox_div(float* __restrict__ vox, const float* __restrict__ counts) {
    int i = blockIdx.x * blockDim.x + threadIdx.x;
    if (i >= MVOX) return;
    float inv = 1.0f / fmaxf(counts[i], 1.0f);
    float4* vp = reinterpret_cast<float4*>(vox + (size_t)i * CIN);
    float4 v = *vp;
    v.x *= inv; v.y *= inv; v.z *= inv; v.w *= inv;
    *vp = v;
}

// ---------------- sparse convs ----------------
__global__ void conv_s1(const float* __restrict__ x, const int* __restrict__ nbrs,
                        const float* __restrict__ W, float* __restrict__ out) {
    int i = blockIdx.x * blockDim.x + threadIdx.x;
    if (i >= MVOX) return;
    float acc[C0];
#pragma unroll
    for (int c = 0; c < C0; c++) acc[c] = 0.f;
    const int* nb = nbrs + (size_t)i * KK;
    for (int k = 0; k < KK; k++) {
        int idx = nb[k];
        if (idx < 0) continue;
        float4 xv = *reinterpret_cast<const float4*>(x + (size_t)idx * CIN);
        const float* wk = W + k * (CIN * C0);
        float xs[4] = {xv.x, xv.y, xv.z, xv.w};
#pragma unroll
        for (int j = 0; j < 4; j++) {
#pragma unroll
            for (int co = 0; co < C0; co++) acc[co] += xs[j] * wk[j * C0 + co];
        }
    }
    float* o = out + (size_t)i * C0;
#pragma unroll
    for (int c = 0; c < C0; c += 4) {
        float4 v; v.x = acc[c]; v.y = acc[c + 1]; v.z = acc[c + 2]; v.w = acc[c + 3];
        *reinterpret_cast<float4*>(o + c) = v;
    }
}

__global__ void conv32(const float* __restrict__ x, const int* __restrict__ nbrs,
                       const float* __restrict__ W, float* __restrict__ out) {
    int i = blockIdx.x * blockDim.x + threadIdx.x;
    if (i >= MVOX) return;
    float acc[C0];
#pragma unroll
    for (int c = 0; c < C0; c++) acc[c] = 0.f;
    const int* nb = nbrs + (size_t)i * KK;
    for (int k = 0; k < KK; k++) {
        int idx = nb[k];
        if (idx < 0) continue;
        const float* xr = x + (size_t)idx * C0;
        const float* wk = W + k * (C0 * C0);
#pragma unroll
        for (int ci = 0; ci < C0; ci += 4) {
            float4 xv = *reinterpret_cast<const float4*>(xr + ci);
            float xs[4] = {xv.x, xv.y, xv.z, xv.w};
#pragma unroll
            for (int j = 0; j < 4; j++) {
#pragma unroll
                for (int co = 0; co < C0; co++) acc[co] += xs[j] * wk[(ci + j) * C0 + co];
            }
        }
    }
    float* o = out + (size_t)i * C0;
#pragma unroll
    for (int c = 0; c < C0; c += 4) {
        float4 v; v.x = acc[c]; v.y = acc[c + 1]; v.z = acc[c + 2]; v.w = acc[c + 3];
        *reinterpret_cast<float4*>(o + c) = v;
    }
}

// ---------------- batch norm ----------------
// sums: [64] = sum[32] | sumsq[32], pre-zeroed
__global__ void bn_stats(const float* __restrict__ x, float* __restrict__ sums) {
    const int total4 = MVOX * C0 / 4;
    int t0 = blockIdx.x * blockDim.x + threadIdx.x;
    int stride = gridDim.x * blockDim.x; // multiple of 8 -> channel quartet fixed
    float s[4] = {0, 0, 0, 0}, q[4] = {0, 0, 0, 0};
    for (int t = t0; t < total4; t += stride) {
        float4 v = reinterpret_cast<const float4*>(x)[t];
        s[0] += v.x; s[1] += v.y; s[2] += v.z; s[3] += v.w;
        q[0] += v.x * v.x; q[1] += v.y * v.y; q[2] += v.z * v.z; q[3] += v.w * v.w;
    }
    // lanes l and l+8 share the same channel quartet
#pragma unroll
    for (int off = 32; off >= 8; off >>= 1) {
#pragma unroll
        for (int j = 0; j < 4; j++) {
            s[j] += __shfl_down(s[j], off);
            q[j] += __shfl_down(q[j], off);
        }
    }
    __shared__ float ls[64];
    if (threadIdx.x < 64) ls[threadIdx.x] = 0.f;
    __syncthreads();
    int lane = threadIdx.x & 63;
    int cb = (threadIdx.x & 7) * 4;
    if (lane < 8) {
#pragma unroll
        for (int j = 0; j < 4; j++) {
            atomicAdd(&ls[cb + j], s[j]);
            atomicAdd(&ls[32 + cb + j], q[j]);
        }
    }
    __syncthreads();
    if (threadIdx.x < 64) atomicAdd(&sums[threadIdx.x], ls[threadIdx.x]);
}

__global__ void bn_finalize(const float* __restrict__ sums, const float* __restrict__ g,
                            const float* __restrict__ b, float* __restrict__ ss) {
    int c = threadIdx.x;
    if (c >= C0) return;
    float mean = sums[c] * (1.0f / (float)MVOX);
    float var = sums[C0 + c] * (1.0f / (float)MVOX) - mean * mean;
    float sc = g[c] * rsqrtf(var + EPS);
    ss[c] = sc;
    ss[C0 + c] = b[c] - mean * sc;
}

__global__ void bn_apply_relu(float* __restrict__ x, const float* __restrict__ ss) {
    int t = blockIdx.x * blockDim.x + threadIdx.x;
    if (t >= MVOX * C0 / 4) return;
    int cb = (t * 4) & (C0 - 1);
    float4 v = reinterpret_cast<float4*>(x)[t];
    v.x = fmaxf(v.x * ss[cb + 0] + ss[C0 + cb + 0], 0.f);
    v.y = fmaxf(v.y * ss[cb + 1] + ss[C0 + cb + 1], 0.f);
    v.z = fmaxf(v.z * ss[cb + 2] + ss[C0 + cb + 2], 0.f);
    v.w = fmaxf(v.w * ss[cb + 3] + ss[C0 + cb + 3], 0.f);
    reinterpret_cast<float4*>(x)[t] = v;
}

// H = relu(bn(A) + Hskip)
__global__ void residual_relu(const float* __restrict__ a, const float* __restrict__ hskip,
                              const float* __restrict__ ss, float* __restrict__ outH) {
    int t = blockIdx.x * blockDim.x + threadIdx.x;
    if (t >= MVOX * C0 / 4) return;
    int cb = (t * 4) & (C0 - 1);
    float4 v = reinterpret_cast<const float4*>(a)[t];
    float4 h = reinterpret_cast<const float4*>(hskip)[t];
    v.x = fmaxf(v.x * ss[cb + 0] + ss[C0 + cb + 0] + h.x, 0.f);
    v.y = fmaxf(v.y * ss[cb + 1] + ss[C0 + cb + 1] + h.y, 0.f);
    v.z = fmaxf(v.z * ss[cb + 2] + ss[C0 + cb + 2] + h.z, 0.f);
    v.w = fmaxf(v.w * ss[cb + 3] + ss[C0 + cb + 3] + h.w, 0.f);
    reinterpret_cast<float4*>(outH)[t] = v;
}

// ---------------- devoxelize + classify ----------------
__global__ void devox_classify(const float* __restrict__ H, const int* __restrict__ idxd,
                               const float* __restrict__ wdev, const float* __restrict__ Wc,
                               const float* __restrict__ bc, float* __restrict__ out) {
    int i = blockIdx.x * blockDim.x + threadIdx.x;
    if (i >= NPTS) return;
    float acc[C0];
#pragma unroll
    for (int c = 0; c < C0; c++) acc[c] = 0.f;
#pragma unroll
    for (int k = 0; k < KD; k++) {
        int idx = idxd[(size_t)i * KD + k];
        if (idx < 0) continue;
        float w = wdev[(size_t)i * KD + k];
        const float4* hr = reinterpret_cast<const float4*>(H + (size_t)idx * C0);
#pragma unroll
        for (int j = 0; j < 8; j++) {
            float4 v = hr[j];
            acc[j * 4 + 0] += w * v.x;
            acc[j * 4 + 1] += w * v.y;
            acc[j * 4 + 2] += w * v.z;
            acc[j * 4 + 3] += w * v.w;
        }
    }
    float o[NCLS];
#pragma unroll
    for (int c = 0; c < NCLS; c++) o[c] = bc[c];
#pragma unroll
    for (int ci = 0; ci < C0; ci++) {
        float xs = acc[ci];
#pragma unroll
        for (int c = 0; c < NCLS; c++) o[c] += xs * Wc[ci * NCLS + c];
    }
    float* op = out + (size_t)i * NCLS;
#pragma unroll
    for (int c = 0; c < NCLS; c++) op[c] = o[c];
}

extern "C" void kernel_launch(void* const* d_in, const int* in_sizes, int n_in,
                              void* d_out, int out_size, void* d_ws, size_t ws_size,
                              hipStream_t stream) {
    const float* point_fea = (const float*)d_in[0];
    const int*   idx_query = (const int*)d_in[1];
    const int*   nbrs      = (const int*)d_in[2];
    const int*   idx_dev   = (const int*)d_in[3];
    const float* w_dev     = (const float*)d_in[4];
    const float* W_s1      = (const float*)d_in[5];
    const float* W_s2      = (const float*)d_in[6];
    const float* g_s1      = (const float*)d_in[7];
    const float* b_s1      = (const float*)d_in[8];
    const float* g_s2      = (const float*)d_in[9];
    const float* b_s2      = (const float*)d_in[10];
    const float* W_r1      = (const float*)d_in[11];
    const float* W_r2      = (const float*)d_in[12];
    const float* g_r1      = (const float*)d_in[13];
    const float* b_r1      = (const float*)d_in[14];
    const float* g_r2      = (const float*)d_in[15];
    const float* b_r2      = (const float*)d_in[16];
    const float* W_c       = (const float*)d_in[17];
    const float* b_c       = (const float*)d_in[18];
    float* out = (float*)d_out;

    float* ws     = (float*)d_ws;
    float* stats  = ws;                      // 256 floats (4 layers x 64)
    float* ss     = ws + 256;                // 256 floats (4 layers x 64)
    float* counts = ws + 512;                // M
    float* vox    = counts + MVOX;           // 4M
    float* A      = vox + (size_t)4 * MVOX;  // 32M
    float* B      = A + (size_t)C0 * MVOX;   // 32M
    float* C      = B + (size_t)C0 * MVOX;   // 32M

    // zero the atomically-accumulated regions: stats(256)+ss(256)+counts(M)+vox(4M)
    hipMemsetAsync(ws, 0, (size_t)(512 + 5 * MVOX) * sizeof(float), stream);

    dim3 blk(256);
    dim3 gN((NPTS + 255) / 256);
    dim3 gM((MVOX + 255) / 256);
    dim3 gE((MVOX * C0 / 4 + 255) / 256);

    vox_accum<<<gN, blk, 0, stream>>>(point_fea, idx_query, counts, vox);
    vox_div<<<gM, blk, 0, stream>>>(vox, counts);

    conv_s1<<<gM, blk, 0, stream>>>(vox, nbrs, W_s1, A);
    bn_stats<<<128, blk, 0, stream>>>(A, stats + 0);
    bn_finalize<<<1, 64, 0, stream>>>(stats + 0, g_s1, b_s1, ss + 0);
    bn_apply_relu<<<gE, blk, 0, stream>>>(A, ss + 0);

    conv32<<<gM, blk, 0, stream>>>(A, nbrs, W_s2, B);
    bn_stats<<<128, blk, 0, stream>>>(B, stats + 64);
    bn_finalize<<<1, 64, 0, stream>>>(stats + 64, g_s2, b_s2, ss + 64);
    bn_apply_relu<<<gE, blk, 0, stream>>>(B, ss + 64);

    conv32<<<gM, blk, 0, stream>>>(B, nbrs, W_r1, C);
    bn_stats<<<128, blk, 0, stream>>>(C, stats + 128);
    bn_finalize<<<1, 64, 0, stream>>>(stats + 128, g_r1, b_r1, ss + 128);
    bn_apply_relu<<<gE, blk, 0, stream>>>(C, ss + 128);

    conv32<<<gM, blk, 0, stream>>>(C, nbrs, W_r2, A);
    bn_stats<<<128, blk, 0, stream>>>(A, stats + 192);
    bn_finalize<<<1, 64, 0, stream>>>(stats + 192, g_r2, b_r2, ss + 192);
    residual_relu<<<gE, blk, 0, stream>>>(A, B, ss + 192, C);

    devox_classify<<<gN, blk, 0, stream>>>(C, idx_dev, w_dev, W_c, b_c, out);
}